// Round 5
// baseline (596.264 us; speedup 1.0000x reference)
//
#include <hip/hip_runtime.h>

#define B 32
#define N 2048
#define K 64
#define C 64
#define R 32

typedef float vf4 __attribute__((ext_vector_type(4)));  // native vector for nontemporal builtin

__device__ __forceinline__ unsigned long long kmax(unsigned long long a, unsigned long long b) {
    return a > b ? a : b;
}

// ---------------- Kernel 1: per-batch top-64 (32 blocks, ~7 us serial prefix) ----------------
__global__ __launch_bounds__(256) void topk_kernel(const float* __restrict__ acc,
                                                   float* __restrict__ out_vals,
                                                   float* __restrict__ out_idxf,
                                                   float* __restrict__ ws_vals,
                                                   int* __restrict__ ws_idx) {
    __shared__ unsigned long long wmax[4];
    const int t = threadIdx.x;
    const int b = blockIdx.x;
    const int lane = t & 63;
    const int wave = t >> 6;
    const float* row = acc + b * N;

    // key = (monotone(f32) << 32) | (N-1-idx): max key == max val, then min idx.
    unsigned long long kr[8];
    unsigned long long m = 0ull;
#pragma unroll
    for (int j = 0; j < 8; ++j) {
        int i = t + 256 * j;
        unsigned int bits = __float_as_uint(row[i]);
        unsigned int u = (bits & 0x80000000u) ? ~bits : (bits | 0x80000000u);
        kr[j] = ((unsigned long long)u << 32) | (unsigned int)(N - 1 - i);
        m = kmax(m, kr[j]);
    }

    for (int s = 0; s < K; ++s) {
        unsigned long long w = m;
#pragma unroll
        for (int off = 32; off; off >>= 1)
            w = kmax(w, __shfl_down(w, off, 64));
        if (lane == 0) wmax[wave] = w;
        __syncthreads();
        unsigned long long best = kmax(kmax(wmax[0], wmax[1]), kmax(wmax[2], wmax[3]));
        if (t == 0) {
            unsigned int u = (unsigned int)(best >> 32);
            unsigned int bits = (u & 0x80000000u) ? (u ^ 0x80000000u) : ~u;
            float v = __uint_as_float(bits);
            int idx = (N - 1) - (int)(best & 0xFFFFFFFFull);
            out_vals[b * K + s] = v;
            out_idxf[b * K + s] = (float)idx;
            ws_vals[b * K + s] = v;
            ws_idx[b * K + s] = idx;
        }
        // Exactly one thread owns `best` (keys unique); it removes it locally.
        if (m == best) {
            unsigned long long nm = 0ull;
#pragma unroll
            for (int j = 0; j < 8; ++j) {
                if (kr[j] == best) kr[j] = 0ull;
                nm = kmax(nm, kr[j]);
            }
            m = nm;
        }
        __syncthreads();  // WAR on wmax
    }
}

// ---------------- Kernel 2: [frob: blocks 0..255] + [zero+insert M: blocks 256..8447] -------
// frob blocks dispatched first so their read-bound work hides under the
// write-bound zero phase. zero+insert writes outer-product values inline
// while zeroing its 8-row slab -> no second pass over M, no scattered RMW.
#define FROB_BLOCKS (B * 8)              // 256
#define ZERO_BLOCKS (B * (N / 8))        // 8192

__global__ __launch_bounds__(256) void fused_frob_zero_insert_kernel(const float* __restrict__ U,
                                                                     const float* __restrict__ ws_vals,
                                                                     const int* __restrict__ ws_idx,
                                                                     float* __restrict__ out_frob,
                                                                     float* __restrict__ M) {
    __shared__ float sv[K];
    __shared__ int si[K];
    const int t = threadIdx.x;

    if (blockIdx.x >= FROB_BLOCKS) {
        // ---- zero+insert: 8 rows (64 KiB) of batch b's M ----
        __shared__ int match[8];
        const int zb = blockIdx.x - FROB_BLOCKS;
        const int b = zb >> 8;
        const int rowblk = zb & 255;
        const int row0 = rowblk * 8;

        if (t < K) {
            sv[t] = ws_vals[b * K + t];
            si[t] = ws_idx[b * K + t];
        }
        if (t < 8) match[t] = -1;
        __syncthreads();
        if (t < K) {
            int d = si[t] - row0;
            if (d >= 0 && d < 8) match[d] = t;  // indices unique -> no race
        }

        float* base = M + ((size_t)b << 22) + ((size_t)row0 << 11);
        vf4* b4 = (vf4*)base;
        const vf4 z = {0.f, 0.f, 0.f, 0.f};
#pragma unroll
        for (int j = 0; j < 16; ++j)
            __builtin_nontemporal_store(z, &b4[t + 256 * j]);

        __syncthreads();  // zero stores (+match writes) ordered before inserts

#pragma unroll
        for (int rr = 0; rr < 8; ++rr) {
            int p = match[rr];
            if (p >= 0 && t < K)
                base[(size_t)rr * N + si[t]] = sv[p] * sv[t];
        }
        return;
    }

    // ---- frob = sum_r (sum_k vals[k]*U[c,idx[k],r])^2 / 2048 ----
    const int b = blockIdx.x >> 3;
    const int cg = blockIdx.x & 7;
    if (t < K) {
        sv[t] = ws_vals[b * K + t];
        si[t] = ws_idx[b * K + t];
    }
    __syncthreads();
    const int r = t & 31;
    const int c = (cg << 3) + (t >> 5);
    const float* Uc = U + (size_t)c * (N * R) + r;  // lanes r contiguous -> coalesced 128B
    float accv = 0.0f;
#pragma unroll 8
    for (int k = 0; k < K; ++k)
        accv = fmaf(sv[k], Uc[(size_t)si[k] * R], accv);
    float x = accv * accv;
#pragma unroll
    for (int off = 16; off; off >>= 1)
        x += __shfl_xor(x, off, 32);
    if (r == 0) out_frob[b * C + c] = x * (1.0f / 2048.0f);
}

extern "C" void kernel_launch(void* const* d_in, const int* in_sizes, int n_in,
                              void* d_out, int out_size, void* d_ws, size_t ws_size,
                              hipStream_t stream) {
    const float* acc = (const float*)d_in[0];
    const float* U = (const float*)d_in[1];
    float* out = (float*)d_out;

    float* out_vals = out;                // [B,K]
    float* out_idxf = out + B * K;        // [B,K] (indices as float)
    float* out_frob = out + 2 * B * K;    // [B,C]
    float* out_M = out + 3 * B * K;       // [B,N,N]

    float* ws_vals = (float*)d_ws;
    int* ws_idx = (int*)((char*)d_ws + B * K * sizeof(float));

    topk_kernel<<<B, 256, 0, stream>>>(acc, out_vals, out_idxf, ws_vals, ws_idx);
    fused_frob_zero_insert_kernel<<<FROB_BLOCKS + ZERO_BLOCKS, 256, 0, stream>>>(
        U, ws_vals, ws_idx, out_frob, out_M);
}

// Round 6
// 571.858 us; speedup vs baseline: 1.0427x; 1.0427x over previous
//
#include <hip/hip_runtime.h>

#define B 32
#define N 2048
#define K 64
#define C 64
#define R 32

typedef float vf4 __attribute__((ext_vector_type(4)));  // native vector for nontemporal builtin

__device__ __forceinline__ unsigned long long kmax(unsigned long long a, unsigned long long b) {
    return a > b ? a : b;
}

// ---------------- Kernel A ------------------------------------------------------------------
// blocks 0..31    : topk for batch b, THEN frob for batch b (all hidden under zero phase)
// blocks 32..8223 : zero one 8-row slab (64 KiB) of M with nontemporal float4 stores
#define ZERO_BLOCKS (B * (N / 8))  // 8192

__global__ __launch_bounds__(256) void fused_topk_frob_zero_kernel(const float* __restrict__ acc,
                                                                   const float* __restrict__ U,
                                                                   float* __restrict__ out_vals,
                                                                   float* __restrict__ out_idxf,
                                                                   float* __restrict__ out_frob,
                                                                   float* __restrict__ ws_vals,
                                                                   int* __restrict__ ws_idx,
                                                                   float* __restrict__ M) {
    const int t = threadIdx.x;

    if (blockIdx.x >= B) {
        // ---- zero 8 rows (64 KiB) of M; store-only, no syncs, max store pipelining ----
        const int zb = blockIdx.x - B;
        const int b = zb >> 8;          // 256 slabs per batch
        const int rowblk = zb & 255;
        vf4* b4 = (vf4*)(M + ((size_t)b << 22) + ((size_t)rowblk << 14));
        const vf4 z = {0.f, 0.f, 0.f, 0.f};
#pragma unroll
        for (int j = 0; j < 16; ++j)
            __builtin_nontemporal_store(z, &b4[t + 256 * j]);
        return;
    }

    // ================= topk (batch b) =================
    __shared__ unsigned long long wmax[4];
    __shared__ float sv[K];
    __shared__ int si[K];
    const int b = blockIdx.x;
    const int lane = t & 63;
    const int wave = t >> 6;
    const float* row = acc + b * N;

    // key = (monotone(f32) << 32) | (N-1-idx): max key == max val, then min idx.
    unsigned long long kr[8];
    unsigned long long m = 0ull;
#pragma unroll
    for (int j = 0; j < 8; ++j) {
        int i = t + 256 * j;
        unsigned int bits = __float_as_uint(row[i]);
        unsigned int u = (bits & 0x80000000u) ? ~bits : (bits | 0x80000000u);
        kr[j] = ((unsigned long long)u << 32) | (unsigned int)(N - 1 - i);
        m = kmax(m, kr[j]);
    }

    for (int s = 0; s < K; ++s) {
        unsigned long long w = m;
#pragma unroll
        for (int off = 32; off; off >>= 1)
            w = kmax(w, __shfl_down(w, off, 64));
        if (lane == 0) wmax[wave] = w;
        __syncthreads();
        unsigned long long best = kmax(kmax(wmax[0], wmax[1]), kmax(wmax[2], wmax[3]));
        if (t == 0) {
            unsigned int u = (unsigned int)(best >> 32);
            unsigned int bits = (u & 0x80000000u) ? (u ^ 0x80000000u) : ~u;
            float v = __uint_as_float(bits);
            int idx = (N - 1) - (int)(best & 0xFFFFFFFFull);
            out_vals[b * K + s] = v;
            out_idxf[b * K + s] = (float)idx;
            ws_vals[b * K + s] = v;
            ws_idx[b * K + s] = idx;
            sv[s] = v;
            si[s] = idx;
        }
        // Exactly one thread owns `best` (keys unique); it removes it locally.
        if (m == best) {
            unsigned long long nm = 0ull;
#pragma unroll
            for (int j = 0; j < 8; ++j) {
                if (kr[j] == best) kr[j] = 0ull;
                nm = kmax(nm, kr[j]);
            }
            m = nm;
        }
        __syncthreads();  // WAR on wmax; also publishes sv[s]/si[s]
    }

    // ================= frob (batch b) — hidden under the zero phase =================
    // thread t: r = t&31, channels c = (t>>5) + 8*cc for cc in [0,8)
    const int r = t & 31;
    const int cbase = t >> 5;
    float accv[8] = {0.f, 0.f, 0.f, 0.f, 0.f, 0.f, 0.f, 0.f};
#pragma unroll 4
    for (int k = 0; k < K; ++k) {
        const float v = sv[k];
        const float* Up = U + (size_t)si[k] * R + r;  // lanes r contiguous -> coalesced 128B
#pragma unroll
        for (int cc = 0; cc < 8; ++cc)
            accv[cc] = fmaf(v, Up[(size_t)(cbase + 8 * cc) * (N * R)], accv[cc]);
    }
#pragma unroll
    for (int cc = 0; cc < 8; ++cc) {
        float x = accv[cc] * accv[cc];
#pragma unroll
        for (int off = 16; off; off >>= 1)
            x += __shfl_xor(x, off, 32);
        if (r == 0) out_frob[b * C + (cbase + 8 * cc)] = x * (1.0f / 2048.0f);
    }
}

// ---------------- Kernel B: scatter only (256 blocks, 2 entries/thread) ---------------------
__global__ __launch_bounds__(256) void scatter_kernel(const float* __restrict__ ws_vals,
                                                      const int* __restrict__ ws_idx,
                                                      float* __restrict__ M) {
    __shared__ float sv[K];
    __shared__ int si[K];
    const int t = threadIdx.x;
    const int b = blockIdx.x >> 3;
    const int cg = blockIdx.x & 7;
    if (t < K) {
        sv[t] = ws_vals[b * K + t];
        si[t] = ws_idx[b * K + t];
    }
    __syncthreads();
    float* Mb = M + ((size_t)b << 22);
#pragma unroll
    for (int q = 0; q < 2; ++q) {
        int p = (cg << 9) + (q << 8) + t;  // [0, 4096)
        int i = p >> 6;
        int j = p & 63;
        Mb[(size_t)si[i] * N + si[j]] = sv[i] * sv[j];  // indices unique -> no race
    }
}

extern "C" void kernel_launch(void* const* d_in, const int* in_sizes, int n_in,
                              void* d_out, int out_size, void* d_ws, size_t ws_size,
                              hipStream_t stream) {
    const float* acc = (const float*)d_in[0];
    const float* U = (const float*)d_in[1];
    float* out = (float*)d_out;

    float* out_vals = out;                // [B,K]
    float* out_idxf = out + B * K;        // [B,K] (indices as float)
    float* out_frob = out + 2 * B * K;    // [B,C]
    float* out_M = out + 3 * B * K;       // [B,N,N]

    float* ws_vals = (float*)d_ws;
    int* ws_idx = (int*)((char*)d_ws + B * K * sizeof(float));

    fused_topk_frob_zero_kernel<<<B + ZERO_BLOCKS, 256, 0, stream>>>(
        acc, U, out_vals, out_idxf, out_frob, ws_vals, ws_idx, out_M);
    scatter_kernel<<<B * 8, 256, 0, stream>>>(ws_vals, ws_idx, out_M);
}

// Round 7
// 551.550 us; speedup vs baseline: 1.0811x; 1.0368x over previous
//
#include <hip/hip_runtime.h>

#define B 32
#define N 2048
#define K 64
#define C 64
#define R 32

typedef float vf4 __attribute__((ext_vector_type(4)));  // native vector for nontemporal builtin

__device__ __forceinline__ unsigned long long kmax(unsigned long long a, unsigned long long b) {
    return a > b ? a : b;
}

// ---------------- Kernel A: [topk: blocks 0..31] + [zero M: blocks 32..2079] ----------------
// topk blocks dispatched first; latency-bound, hides under the write-bound zero
// phase. Zero blocks are store-only (no LDS, no syncs — R5 showed any store-drain
// sync in the zero path costs ~30 us). 2048 zero blocks x 256 KiB each.
#define ZERO_BLOCKS 2048

__global__ __launch_bounds__(256) void fused_topk_zero_kernel(const float* __restrict__ acc,
                                                              float* __restrict__ out_vals,
                                                              float* __restrict__ out_idxf,
                                                              float* __restrict__ ws_vals,
                                                              int* __restrict__ ws_idx,
                                                              float* __restrict__ M) {
    const int t = threadIdx.x;

    if (blockIdx.x >= B) {
        // ---- zero 256 KiB of M (64 nontemporal float4 stores per thread) ----
        const int zb = blockIdx.x - B;
        const int b = zb >> 6;           // 64 chunks per batch
        const int chunk = zb & 63;
        vf4* b4 = (vf4*)(M + ((size_t)b << 22) + ((size_t)chunk << 16));
        const vf4 z = {0.f, 0.f, 0.f, 0.f};
#pragma unroll
        for (int j = 0; j < 64; ++j)
            __builtin_nontemporal_store(z, &b4[t + 256 * j]);
        return;
    }

    // ---- per-batch top-64 (sorted desc, lowest-index tie-break) ----
    __shared__ unsigned long long wmax[4];
    const int b = blockIdx.x;
    const int lane = t & 63;
    const int wave = t >> 6;
    const float* row = acc + b * N;

    // key = (monotone(f32) << 32) | (N-1-idx): max key == max val, then min idx.
    unsigned long long kr[8];
    unsigned long long m = 0ull;
#pragma unroll
    for (int j = 0; j < 8; ++j) {
        int i = t + 256 * j;
        unsigned int bits = __float_as_uint(row[i]);
        unsigned int u = (bits & 0x80000000u) ? ~bits : (bits | 0x80000000u);
        kr[j] = ((unsigned long long)u << 32) | (unsigned int)(N - 1 - i);
        m = kmax(m, kr[j]);
    }

    for (int s = 0; s < K; ++s) {
        unsigned long long w = m;
#pragma unroll
        for (int off = 32; off; off >>= 1)
            w = kmax(w, __shfl_down(w, off, 64));
        if (lane == 0) wmax[wave] = w;
        __syncthreads();
        unsigned long long best = kmax(kmax(wmax[0], wmax[1]), kmax(wmax[2], wmax[3]));
        if (t == 0) {
            unsigned int u = (unsigned int)(best >> 32);
            unsigned int bits = (u & 0x80000000u) ? (u ^ 0x80000000u) : ~u;
            float v = __uint_as_float(bits);
            int idx = (N - 1) - (int)(best & 0xFFFFFFFFull);
            out_vals[b * K + s] = v;
            out_idxf[b * K + s] = (float)idx;
            ws_vals[b * K + s] = v;
            ws_idx[b * K + s] = idx;
        }
        // Exactly one thread owns `best` (keys unique); it removes it locally.
        if (m == best) {
            unsigned long long nm = 0ull;
#pragma unroll
            for (int j = 0; j < 8; ++j) {
                if (kr[j] == best) kr[j] = 0ull;
                nm = kmax(nm, kr[j]);
            }
            m = nm;
        }
        __syncthreads();  // WAR on wmax
    }
}

// ---------------- Kernel B: frob + scatter spread over B*8 = 256 blocks ---------------------
__global__ __launch_bounds__(256) void fused_frob_scatter_kernel(const float* __restrict__ U,
                                                                 const float* __restrict__ ws_vals,
                                                                 const int* __restrict__ ws_idx,
                                                                 float* __restrict__ out_frob,
                                                                 float* __restrict__ M) {
    __shared__ float sv[K];
    __shared__ int si[K];
    const int t = threadIdx.x;
    const int b = blockIdx.x >> 3;
    const int cg = blockIdx.x & 7;
    if (t < K) {
        sv[t] = ws_vals[b * K + t];
        si[t] = ws_idx[b * K + t];
    }
    __syncthreads();

    // ---- scatter: entries p in [cg*512, cg*512+512) of the 64x64 outer product ----
    float* Mb = M + ((size_t)b << 22);
#pragma unroll
    for (int q = 0; q < 2; ++q) {
        int p = (cg << 9) + (q << 8) + t;  // [0, 4096)
        int i = p >> 6;
        int j = p & 63;
        Mb[(size_t)si[i] * N + si[j]] = sv[i] * sv[j];  // indices unique -> no race
    }

    // ---- frob = sum_r (sum_k vals[k]*U[c,idx[k],r])^2 / 2048 ----
    const int r = t & 31;
    const int c = (cg << 3) + (t >> 5);
    const float* Uc = U + (size_t)c * (N * R) + r;  // lanes r contiguous -> coalesced 128B
    float accv = 0.0f;
#pragma unroll 8
    for (int k = 0; k < K; ++k)
        accv = fmaf(sv[k], Uc[(size_t)si[k] * R], accv);
    float x = accv * accv;
#pragma unroll
    for (int off = 16; off; off >>= 1)
        x += __shfl_xor(x, off, 32);
    if (r == 0) out_frob[b * C + c] = x * (1.0f / 2048.0f);
}

extern "C" void kernel_launch(void* const* d_in, const int* in_sizes, int n_in,
                              void* d_out, int out_size, void* d_ws, size_t ws_size,
                              hipStream_t stream) {
    const float* acc = (const float*)d_in[0];
    const float* U = (const float*)d_in[1];
    float* out = (float*)d_out;

    float* out_vals = out;                // [B,K]
    float* out_idxf = out + B * K;        // [B,K] (indices as float)
    float* out_frob = out + 2 * B * K;    // [B,C]
    float* out_M = out + 3 * B * K;       // [B,N,N]

    float* ws_vals = (float*)d_ws;
    int* ws_idx = (int*)((char*)d_ws + B * K * sizeof(float));

    fused_topk_zero_kernel<<<B + ZERO_BLOCKS, 256, 0, stream>>>(acc, out_vals, out_idxf,
                                                                ws_vals, ws_idx, out_M);
    fused_frob_scatter_kernel<<<B * 8, 256, 0, stream>>>(U, ws_vals, ws_idx,
                                                         out_frob, out_M);
}